// Round 1
// baseline (191.354 us; speedup 1.0000x reference)
//
#include <hip/hip_runtime.h>

// Problem shape (fixed by the reference): B=32, T=4096, E=256.
#define NROWS 32
#define TLEN  4096
#define EDIM  256
#define PER   (TLEN / 256)      // tokens per thread in the scan = 16
#define SEGS_PER_BLOCK 4        // one segment per wave, 4 waves/block

// ---------------------------------------------------------------------------
// Fused kernel: each block (256 threads) handles 4 segments of one row.
// Phase 1: block redundantly scans its row's batch_x (16 KB, L2-hot across
//          the 64 blocks sharing the row). Flags are packed into a 16-bit
//          mask (no flags[16] array) to keep VGPRs low.
// Phase 2: wave w mean-pools segment k0+w; lane l owns features [4l,4l+4).
//          cnt==16 fast path: two batches of 8 independent loads.
// __launch_bounds__(256, 8): pin 8 waves/SIMD (VGPR<=64) so all 8 blocks/CU
// are co-resident in one scheduling round -> enough TLP to saturate HBM.
// ---------------------------------------------------------------------------
__global__ __launch_bounds__(256, 8) void fused_pool_kernel(
    const float* __restrict__ nn,
    const int*  __restrict__ batch_x,
    int maxlen, int nb_per_row,
    float* __restrict__ out,         // [B, maxlen, E]
    float* __restrict__ n_cuts_out)  // [B] fp32 tail of d_out
{
    const int tid  = threadIdx.x;
    const int lane = tid & 63;
    const int w    = tid >> 6;
    const int blk  = blockIdx.x;
    const int b    = blk / nb_per_row;
    const int k0   = (blk - b * nb_per_row) * SEGS_PER_BLOCK;

    // ---- Phase 1: scan row b ----
    __shared__ int s_cuts[TLEN];     // worst-case T cuts
    __shared__ int s_wsum[4];

    const int* row = batch_x + (long long)b * TLEN;
    const int t0 = tid * PER;

    // pack the 16 flags into a bitmask (saves 15 VGPRs vs int flags[16])
    unsigned mask = 0;
#pragma unroll
    for (int j = 0; j < PER; j += 4) {
        const int4 v = *(const int4*)(row + t0 + j);   // 64B-aligned
        mask |= (unsigned)(v.x == 1) << (j + 0);
        mask |= (unsigned)(v.y == 1) << (j + 1);
        mask |= (unsigned)(v.z == 1) << (j + 2);
        mask |= (unsigned)(v.w == 1) << (j + 3);
    }
    const int local = __popc(mask);

    // wave inclusive prefix (6 shuffle steps)
    int incl = local;
#pragma unroll
    for (int d = 1; d < 64; d <<= 1) {
        const int v = __shfl_up(incl, d, 64);
        if (lane >= d) incl += v;
    }
    if (lane == 63) s_wsum[w] = incl;
    __syncthreads();
    const int s0 = s_wsum[0], s1 = s_wsum[1], s2 = s_wsum[2], s3 = s_wsum[3];
    const int wbase = (w > 0 ? s0 : 0) + (w > 1 ? s1 : 0) + (w > 2 ? s2 : 0);
    const int ncuts = s0 + s1 + s2 + s3;

    int idx = wbase + incl - local;  // exclusive prefix
    unsigned m = mask;
    while (m) {                       // one iteration per set flag
        const int j = __ffs(m) - 1;
        m &= m - 1;
        s_cuts[idx++] = t0 + j;
    }
    __syncthreads();

    if (k0 == 0 && tid == 0) n_cuts_out[b] = (float)ncuts;

    // ---- Phase 2: pool segment k = k0 + w ----
    const int k = k0 + w;
    if (k >= maxlen) return;

    float4 acc = make_float4(0.f, 0.f, 0.f, 0.f);
    if (k < ncuts) {
        const int start = (k == 0) ? 0 : (s_cuts[k - 1] + 1);
        const int end   = s_cuts[k];                  // inclusive
        const int cnt   = end - start + 1;
        const float* base = nn + ((long long)b * TLEN + start) * EDIM + lane * 4;

        if (cnt == 16) {
            // fast path: two batches of 8 independent loads (32 VGPRs live,
            // vs 64 for a single 16-deep batch)
            float4 v[8];
#pragma unroll
            for (int t = 0; t < 8; ++t)
                v[t] = *(const float4*)(base + (long long)t * EDIM);
#pragma unroll
            for (int s = 1; s < 8; s <<= 1)
#pragma unroll
                for (int t = 0; t < 8; t += 2 * s) {
                    v[t].x += v[t + s].x; v[t].y += v[t + s].y;
                    v[t].z += v[t + s].z; v[t].w += v[t + s].w;
                }
            const float4 sum0 = v[0];
#pragma unroll
            for (int t = 0; t < 8; ++t)
                v[t] = *(const float4*)(base + (long long)(8 + t) * EDIM);
#pragma unroll
            for (int s = 1; s < 8; s <<= 1)
#pragma unroll
                for (int t = 0; t < 8; t += 2 * s) {
                    v[t].x += v[t + s].x; v[t].y += v[t + s].y;
                    v[t].z += v[t + s].z; v[t].w += v[t + s].w;
                }
            const float inv = 1.0f / 16.0f;
            acc.x = (sum0.x + v[0].x) * inv;
            acc.y = (sum0.y + v[0].y) * inv;
            acc.z = (sum0.z + v[0].z) * inv;
            acc.w = (sum0.w + v[0].w) * inv;
        } else {
            float4 a0 = make_float4(0.f, 0.f, 0.f, 0.f);
            float4 a1 = a0, a2 = a0, a3 = a0;
            int t = 0;
            for (; t + 4 <= cnt; t += 4) {
                const float4 v0 = *(const float4*)(base + (long long)(t + 0) * EDIM);
                const float4 v1 = *(const float4*)(base + (long long)(t + 1) * EDIM);
                const float4 v2 = *(const float4*)(base + (long long)(t + 2) * EDIM);
                const float4 v3 = *(const float4*)(base + (long long)(t + 3) * EDIM);
                a0.x += v0.x; a0.y += v0.y; a0.z += v0.z; a0.w += v0.w;
                a1.x += v1.x; a1.y += v1.y; a1.z += v1.z; a1.w += v1.w;
                a2.x += v2.x; a2.y += v2.y; a2.z += v2.z; a2.w += v2.w;
                a3.x += v3.x; a3.y += v3.y; a3.z += v3.z; a3.w += v3.w;
            }
            for (; t < cnt; ++t) {
                const float4 v = *(const float4*)(base + (long long)t * EDIM);
                a0.x += v.x; a0.y += v.y; a0.z += v.z; a0.w += v.w;
            }
            const float inv = 1.0f / (float)cnt;
            acc.x = ((a0.x + a1.x) + (a2.x + a3.x)) * inv;
            acc.y = ((a0.y + a1.y) + (a2.y + a3.y)) * inv;
            acc.z = ((a0.z + a1.z) + (a2.z + a3.z)) * inv;
            acc.w = ((a0.w + a1.w) + (a2.w + a3.w)) * inv;
        }
    }
    float4* o = (float4*)(out + ((long long)b * maxlen + k) * EDIM) + lane;
    *o = acc;
}

extern "C" void kernel_launch(void* const* d_in, const int* in_sizes, int n_in,
                              void* d_out, int out_size, void* d_ws, size_t ws_size,
                              hipStream_t stream) {
    const float* nn_outs = (const float*)d_in[0];
    const int*   batch_x = (const int*)d_in[1];
    float* out = (float*)d_out;

    const int B = NROWS;
    const int maxlen = (out_size - B) / (B * EDIM);      // 256
    float* n_cuts_out = out + (size_t)B * maxlen * EDIM; // tail of d_out

    const int nb_per_row = (maxlen + SEGS_PER_BLOCK - 1) / SEGS_PER_BLOCK;  // 64
    const int blocks = B * nb_per_row;                                      // 2048

    fused_pool_kernel<<<blocks, 256, 0, stream>>>(nn_outs, batch_x,
                                                  maxlen, nb_per_row,
                                                  out, n_cuts_out);
}